// Round 2
// baseline (8698.917 us; speedup 1.0000x reference)
//
#include <hip/hip_runtime.h>
#include <hip/hip_bf16.h>

#define T_ 64
#define DETER_ 4096
#define GRUN 12288

typedef __attribute__((ext_vector_type(8))) __bf16 bf16x8;
typedef __attribute__((ext_vector_type(4))) float f32x4;
typedef __attribute__((ext_vector_type(8))) unsigned short u16x8;
typedef __attribute__((ext_vector_type(4))) unsigned short u16x4;

__device__ inline unsigned short f2bf(float f) {
    union { float f; unsigned u; } x; x.f = f;
    unsigned r = x.u + 0x7fffu + ((x.u >> 16) & 1u);
    return (unsigned short)(r >> 16);
}
__device__ inline float sigmoidf_(float v) { return 1.f / (1.f + __expf(-v)); }
__device__ inline float siluf_(float v)    { return v / (1.f + __expf(-v)); }
__device__ inline float softplusf_(float v){ return fmaxf(v, 0.f) + __logf(1.f + __expf(-fabsf(v))); }
__device__ inline float tanhf_(float v)    { return 2.f / (1.f + __expf(-2.f * v)) - 1.f; }

__device__ inline void barrier_() {
    asm volatile("" ::: "memory");
    __builtin_amdgcn_s_barrier();
    asm volatile("" ::: "memory");
}
template <int N> __device__ inline void vmwaitN() {
    asm volatile("s_waitcnt vmcnt(%0)" :: "i"(N) : "memory");
}
__device__ inline void lgkmwait_() {
    asm volatile("s_waitcnt lgkmcnt(0)" ::: "memory");
}

// ---------------- prep kernels ----------------

// Pack W[K,N] (fp32 row-major) into MFMA B-frag-linear bf16.
__global__ __launch_bounds__(256) void k_pack(const float* __restrict__ W,
                                              unsigned short* __restrict__ dst,
                                              int K, int N) {
    long fid = (long)blockIdx.x * 256 + threadIdx.x;
    long nfr = (long)K * N / 8;
    if (fid >= nfr) return;
    int lane = (int)(fid & 63);
    long tile = fid >> 6;
    int ktiles = K >> 5;
    int k_t = (int)(tile % ktiles);
    int n_t = (int)(tile / ktiles);
    int c = lane & 15, kb = lane >> 4;
    int k0 = k_t * 32 + kb * 8;
    int n = n_t * 16 + c;
    unsigned short v[8];
#pragma unroll
    for (int i = 0; i < 8; i++) v[i] = f2bf(W[(long)(k0 + i) * N + n]);
    *reinterpret_cast<u16x8*>(dst + fid * 8) = *reinterpret_cast<u16x8*>(v);
}

__global__ __launch_bounds__(256) void k_conv(const float* __restrict__ s,
                                              unsigned short* __restrict__ d, long n) {
    long i = ((long)blockIdx.x * 256 + threadIdx.x) * 4;
    if (i >= n) return;
    f32x4 v = *reinterpret_cast<const f32x4*>(s + i);
    unsigned short o[4];
#pragma unroll
    for (int k = 0; k < 4; k++) o[k] = f2bf(v[k]);
    *reinterpret_cast<u16x4*>(d + i) = *reinterpret_cast<u16x4*>(o);
}

__global__ __launch_bounds__(256) void k_copy(const float* __restrict__ s,
                                              float* __restrict__ d, long n) {
    long i = ((long)blockIdx.x * 256 + threadIdx.x) * 4;
    if (i >= n) return;
    *reinterpret_cast<f32x4*>(d + i) = *reinterpret_cast<const f32x4*>(s + i);
}

// ---------------- staging helpers ----------------

// global -> LDS async, XOR-swizzled source so swizzled ds_read is conflict-lite.
// LDS chunk layout: 32 rows x CW cols bf16, row-linear, byte swizzle: cb ^ ((row&7)<<4)
template <int CW>
__device__ inline void stage_glds(unsigned short* chunk, const unsigned short* __restrict__ src,
                                  long ld, long k0) {
    constexpr int NI = (32 * CW * 2) / 4096;   // 1KB per wave-instr
    int wv = (int)threadIdx.x >> 6, lane = (int)threadIdx.x & 63;
#pragma unroll
    for (int i = 0; i < NI; ++i) {
        int obase = (wv * NI + i) << 10;
        int o = obase + lane * 16;
        int row = o / (CW * 2);
        int cb = o - row * (CW * 2);
        int gb = cb ^ ((row & 7) << 4);
        const char* ga = (const char*)(src + (long)row * ld + k0) + gb;
        __builtin_amdgcn_global_load_lds(
            (const __attribute__((address_space(1))) void*)ga,
            (__attribute__((address_space(3))) void*)(chunk + (obase >> 1)),
            16, 0, 0);
    }
}

// LN(raw)*g+b -> SiLU -> bf16, ds_write with the same swizzle. CW=512 only.
__device__ inline void stage_ln512(unsigned short* chunk, const float* __restrict__ raw,
                                   int ld, int col0,
                                   const float* __restrict__ g, const float* __restrict__ b,
                                   const float* s_mean, const float* s_rstd) {
    int tid = threadIdx.x;
#pragma unroll
    for (int i = 0; i < 8; ++i) {
        int e = tid * 8 + i * 2048;
        int row = e >> 9, col = e & 511;
        float m = s_mean[row], rs = s_rstd[row];
        const float* sp = raw + (long)row * ld + col0 + col;
        unsigned short pk[8];
#pragma unroll
        for (int j = 0; j < 8; ++j) {
            float ln = (sp[j] - m) * rs * g[col0 + col + j] + b[col0 + col + j];
            pk[j] = f2bf(siluf_(ln));
        }
        int dcol = col ^ ((row & 7) << 3);
        *reinterpret_cast<u16x8*>(chunk + row * 512 + dcol) = *reinterpret_cast<u16x8*>(pk);
    }
}

// MFMA over one chunk: one 16-row half (row = rh*16+c), 16 cols, full chunk K.
template <int CW>
__device__ inline void mfma_rh(const unsigned short* chunk, int row, int kb,
                               const unsigned short* __restrict__ bp, f32x4& acc) {
    constexpr int NKT = CW / 32;
    const unsigned short* ap = chunk + row * CW;
    int sw = (row & 7) << 3;
#pragma unroll
    for (int kt = 0; kt < NKT; ++kt) {
        bf16x8 a = *reinterpret_cast<const bf16x8*>(ap + ((kb * 8 + kt * 32) ^ sw));
        bf16x8 b = *reinterpret_cast<const bf16x8*>(bp + (long)kt * 512);
        acc = __builtin_amdgcn_mfma_f32_16x16x32_bf16(a, b, acc, 0, 0, 0);
    }
}

// ---------------- generic 32-row GEMM kernel ----------------
// Block: 256 thr / 4 waves; out tile 32 rows x 32 cols at (blockIdx.y*32, blockIdx.x*32).
// NG chunks staged via global_load_lds from srcA (bf16); NL chunks (CW=512) staged as
// LN+SiLU from lnraw fp32 (B-ktiles 0..NL*16 for those; glds chunks at ktg0+).
template <int CW, int NG, int NL>
__global__ __launch_bounds__(256) void k_gemm32(
    const unsigned short* __restrict__ Bp, int Ktiles, int ktg0,
    const unsigned short* __restrict__ srcA, long ldA,
    const float* __restrict__ lnraw, int lnld,
    const float* __restrict__ g_ln, const float* __restrict__ b_ln,
    const float* __restrict__ pstats, int nslab_in,
    const float* __restrict__ addin, long addin_ld,
    float* __restrict__ outp, long out_ld,
    float* __restrict__ partials, long prows)
{
    constexpr int NCH = NG + NL;
    constexpr int NI = (32 * CW * 2) / 4096;
    __shared__ __align__(16) unsigned short sb[2][32 * CW];
    __shared__ float s_out[32][34];
    __shared__ float s_mean[32], s_rstd[32];
    int tid = threadIdx.x;
    if (NL > 0) {
        if (tid < 32) {
            float s = 0.f, q = 0.f;
            for (int j = 0; j < nslab_in; ++j) {
                s += pstats[((long)j * 32 + tid) * 2];
                q += pstats[((long)j * 32 + tid) * 2 + 1];
            }
            float m = s * (1.f / 1024.f);
            s_mean[tid] = m;
            s_rstd[tid] = rsqrtf(q * (1.f / 1024.f) - m * m + 1e-3f);
        }
        __syncthreads();
    }
    int rowbase = blockIdx.y * 32;
    const unsigned short* srcAr = srcA + (long)rowbase * ldA;
    int lane = tid & 63, wv = tid >> 6;
    int nt = wv >> 1, rh = wv & 1;
    int c = lane & 15, kb = lane >> 4;
    int mrow = rh * 16 + c;
    long ntg = (long)blockIdx.x * 2 + nt;
    const unsigned short* bbase = Bp + (long)ntg * Ktiles * 512 + lane * 8;
    f32x4 acc = {0.f, 0.f, 0.f, 0.f};
    stage_glds<CW>(sb[0], srcAr, ldA, 0);
    for (int ch = 0; ch < NCH; ++ch) {
        int nx = ch + 1;
        if (nx < NG) stage_glds<CW>(sb[nx & 1], srcAr, ldA, (long)nx * CW);
        else if (nx < NCH) stage_ln512(sb[nx & 1], lnraw, lnld, (nx - NG) * 512,
                                       g_ln, b_ln, s_mean, s_rstd);
        if (ch < NG) { if (nx < NG) vmwaitN<NI>(); else vmwaitN<0>(); }
        if (nx >= NG && nx < NCH) lgkmwait_();
        barrier_();
        int kt0 = (ch < NG) ? (ktg0 + ch * (CW / 32)) : ((ch - NG) * 16);
        mfma_rh<CW>(sb[ch & 1], mrow, kb, bbase + (long)kt0 * 512, acc);
        barrier_();
    }
    __syncthreads();
#pragma unroll
    for (int j = 0; j < 4; ++j) s_out[rh * 16 + kb * 4 + j][nt * 16 + c] = acc[j];
    __syncthreads();
    int orow = tid >> 3, c4 = (tid & 7) * 4;
    long rg = rowbase + orow;
    float v[4]; float s = 0.f, q = 0.f;
#pragma unroll
    for (int i = 0; i < 4; ++i) {
        float x = s_out[orow][c4 + i];
        if (addin) x += addin[rg * addin_ld + blockIdx.x * 32 + c4 + i];
        v[i] = x; s += x; q += x * x;
    }
#pragma unroll
    for (int i = 0; i < 4; ++i) outp[rg * out_ld + blockIdx.x * 32 + c4 + i] = v[i];
    if (partials) {
#pragma unroll
        for (int m = 1; m < 8; m <<= 1) { s += __shfl_xor(s, m); q += __shfl_xor(q, m); }
        if ((tid & 7) == 0) {
            partials[((long)blockIdx.x * prows + rg) * 2] = s;
            partials[((long)blockIdx.x * prows + rg) * 2 + 1] = q;
        }
    }
}

// ---------------- GRU gate finalize ----------------
__global__ __launch_bounds__(256) void k_deter(const float* __restrict__ G_raw,
                                               const float* __restrict__ pg,
                                               const float* __restrict__ g_gru,
                                               const float* __restrict__ b_gru,
                                               float* __restrict__ deter_f32,
                                               unsigned short* __restrict__ deter_bf16,
                                               unsigned short* __restrict__ deter_allb,
                                               float* __restrict__ out, int t) {
    __shared__ float s_mean[32], s_rstd[32];
    __shared__ float s_red[2][8][32];
    int tid = threadIdx.x;
    {
        int r = tid & 31, g = tid >> 5;
        float s = 0.f, q = 0.f;
        for (int j = g; j < 384; j += 8) {
            s += pg[((long)j * 32 + r) * 2];
            q += pg[((long)j * 32 + r) * 2 + 1];
        }
        s_red[0][g][r] = s; s_red[1][g][r] = q;
    }
    __syncthreads();
    if (tid < 32) {
        float s = 0.f, q = 0.f;
#pragma unroll
        for (int g = 0; g < 8; ++g) { s += s_red[0][g][tid]; q += s_red[1][g][tid]; }
        float m = s * (1.f / 12288.f);
        s_mean[tid] = m;
        s_rstd[tid] = rsqrtf(q * (1.f / 12288.f) - m * m + 1e-3f);
    }
    __syncthreads();
    int eid = blockIdx.x * 256 + tid;
    int b = eid >> 10;
    int j = (eid & 1023) * 4;
    const float* gr = G_raw + (long)b * GRUN;
    f32x4 r4 = *reinterpret_cast<const f32x4*>(gr + j);
    f32x4 c4 = *reinterpret_cast<const f32x4*>(gr + 4096 + j);
    f32x4 u4 = *reinterpret_cast<const f32x4*>(gr + 8192 + j);
    f32x4 d4 = *reinterpret_cast<const f32x4*>(deter_f32 + (long)b * DETER_ + j);
    float m = s_mean[b], rs = s_rstd[b];
    f32x4 nd;
    unsigned short db[4];
#pragma unroll
    for (int i = 0; i < 4; i++) {
        float lr = (r4[i] - m) * rs * g_gru[j + i] + b_gru[j + i];
        float lc = (c4[i] - m) * rs * g_gru[4096 + j + i] + b_gru[4096 + j + i];
        float lu = (u4[i] - m) * rs * g_gru[8192 + j + i] + b_gru[8192 + j + i];
        float reset = sigmoidf_(lr);
        float cand = tanhf_(reset * lc);
        float upd = sigmoidf_(lu - 1.f);
        float dn = upd * cand + (1.f - upd) * d4[i];
        nd[i] = dn; db[i] = f2bf(dn);
    }
    *reinterpret_cast<f32x4*>(deter_f32 + (long)b * DETER_ + j) = nd;
    *reinterpret_cast<u16x4*>(deter_bf16 + (long)b * DETER_ + j) = *reinterpret_cast<u16x4*>(db);
    long orow = (long)b * T_ + t;
    *reinterpret_cast<u16x4*>(deter_allb + orow * DETER_ + j) = *reinterpret_cast<u16x4*>(db);
    *reinterpret_cast<f32x4*>(out + orow * 10240 + j) = nd;
}

// ---------------- posterior stats + sample (critical path) ----------------
__global__ __launch_bounds__(256) void k_statsq(
    const unsigned short* __restrict__ Bp, const float* __restrict__ hq_raw,
    const float* __restrict__ ph,
    const float* __restrict__ g_oo, const float* __restrict__ b_oo,
    const float* __restrict__ bias,
    const float* __restrict__ noise, float* __restrict__ out,
    unsigned short* __restrict__ stochb, int t)
{
    __shared__ __align__(16) unsigned short sb[2][32 * 512];
    __shared__ float s_out[32][66];
    __shared__ float s_mean[32], s_rstd[32];
    int tid = threadIdx.x;
    if (tid < 32) {
        float s = 0.f, q = 0.f;
        for (int j = 0; j < 32; ++j) {
            s += ph[((long)j * 32 + tid) * 2];
            q += ph[((long)j * 32 + tid) * 2 + 1];
        }
        float m = s * (1.f / 1024.f);
        s_mean[tid] = m;
        s_rstd[tid] = rsqrtf(q * (1.f / 1024.f) - m * m + 1e-3f);
    }
    __syncthreads();
    int lane = tid & 63, wv = tid >> 6;
    int part = wv >> 1, nt = wv & 1;
    int c = lane & 15, kb = lane >> 4;
    int s_ = blockIdx.x;
    long ntg = (long)part * 64 + s_ * 2 + nt;
    const unsigned short* bbase = Bp + ntg * 32 * 512 + lane * 8;
    f32x4 acc0 = {0.f,0.f,0.f,0.f}, acc1 = {0.f,0.f,0.f,0.f};
    stage_ln512(sb[0], hq_raw, 1024, 0, g_oo, b_oo, s_mean, s_rstd);
    for (int ch = 0; ch < 2; ++ch) {
        if (ch == 0) stage_ln512(sb[1], hq_raw, 1024, 512, g_oo, b_oo, s_mean, s_rstd);
        lgkmwait_();
        barrier_();
        const unsigned short* bp = bbase + (long)ch * 16 * 512;
        mfma_rh<512>(sb[ch], c, kb, bp, acc0);
        mfma_rh<512>(sb[ch], 16 + c, kb, bp, acc1);
        barrier_();
    }
    __syncthreads();
    float bv = bias[ntg * 16 + c];
#pragma unroll
    for (int j = 0; j < 4; ++j) {
        s_out[kb * 4 + j][part * 32 + nt * 16 + c] = acc0[j] + bv;
        s_out[16 + kb * 4 + j][part * 32 + nt * 16 + c] = acc1[j] + bv;
    }
    __syncthreads();
    int r = tid >> 3, j0 = (tid & 7) * 4;
    long orow = (long)r * T_ + t;
#pragma unroll
    for (int i = 0; i < 4; ++i) {
        int j = j0 + i;
        float mean = s_out[r][j];
        float sd = softplusf_(s_out[r][32 + j]) + 0.1f;
        int cg = s_ * 32 + j;
        float st = mean + sd * noise[orow * 1024 + cg];
        float* op = out + orow * 10240;
        op[4096 + cg] = st; op[5120 + cg] = mean; op[6144 + cg] = sd;
        stochb[r * 1024 + cg] = f2bf(st);
    }
}

// ---------------- batched prior stats + sample (off critical path) ----------------
__global__ __launch_bounds__(256) void k_bstats(
    const unsigned short* __restrict__ Bp, const unsigned short* __restrict__ h_pb,
    const float* __restrict__ bias, const float* __restrict__ noise,
    float* __restrict__ out)
{
    __shared__ __align__(16) unsigned short sb[2][32 * 512];
    __shared__ float s_out[32][66];
    int tid = threadIdx.x;
    int lane = tid & 63, wv = tid >> 6;
    int part = wv >> 1, nt = wv & 1;
    int c = lane & 15, kb = lane >> 4;
    int s_ = blockIdx.x, rowbase = blockIdx.y * 32;
    const unsigned short* A = h_pb + (long)rowbase * 1024;
    long ntg = (long)part * 64 + s_ * 2 + nt;
    const unsigned short* bbase = Bp + ntg * 32 * 512 + lane * 8;
    f32x4 acc0 = {0.f,0.f,0.f,0.f}, acc1 = {0.f,0.f,0.f,0.f};
    stage_glds<512>(sb[0], A, 1024, 0);
    for (int ch = 0; ch < 2; ++ch) {
        if (ch == 0) { stage_glds<512>(sb[1], A, 1024, 512); vmwaitN<8>(); }
        else vmwaitN<0>();
        barrier_();
        const unsigned short* bp = bbase + (long)ch * 16 * 512;
        mfma_rh<512>(sb[ch], c, kb, bp, acc0);
        mfma_rh<512>(sb[ch], 16 + c, kb, bp, acc1);
        barrier_();
    }
    __syncthreads();
    float bv = bias[ntg * 16 + c];
#pragma unroll
    for (int j = 0; j < 4; ++j) {
        s_out[kb * 4 + j][part * 32 + nt * 16 + c] = acc0[j] + bv;
        s_out[16 + kb * 4 + j][part * 32 + nt * 16 + c] = acc1[j] + bv;
    }
    __syncthreads();
    int r = tid >> 3, j0 = (tid & 7) * 4;
    long orow = rowbase + r;
#pragma unroll
    for (int i = 0; i < 4; ++i) {
        int j = j0 + i;
        float mean = s_out[r][j];
        float sd = softplusf_(s_out[r][32 + j]) + 0.1f;
        int cg = s_ * 32 + j;
        float st = mean + sd * noise[orow * 1024 + cg];
        float* op = out + orow * 10240;
        op[7168 + cg] = st; op[8192 + cg] = mean; op[9216 + cg] = sd;
    }
}

// finalize h_p: LN+SiLU -> bf16 for the batched prior stats GEMM
__global__ __launch_bounds__(256) void k_bfin(const float* __restrict__ hp_raw,
                                              const float* __restrict__ pbh,
                                              const float* __restrict__ g_io,
                                              const float* __restrict__ b_io,
                                              unsigned short* __restrict__ h_pb) {
    int row = blockIdx.x * 8 + ((int)threadIdx.x >> 5);
    int l = threadIdx.x & 31;
    float s = pbh[((long)l * 2048 + row) * 2];
    float q = pbh[((long)l * 2048 + row) * 2 + 1];
#pragma unroll
    for (int m = 16; m; m >>= 1) { s += __shfl_xor(s, m, 32); q += __shfl_xor(q, m, 32); }
    float mn = s * (1.f / 1024.f);
    float rs = rsqrtf(q * (1.f / 1024.f) - mn * mn + 1e-3f);
#pragma unroll
    for (int i = 0; i < 8; ++i) {
        int col = i * 128 + l * 4;
        f32x4 v = *reinterpret_cast<const f32x4*>(hp_raw + (long)row * 1024 + col);
        unsigned short pk[4];
#pragma unroll
        for (int j = 0; j < 4; ++j) {
            float ln = (v[j] - mn) * rs * g_io[col + j] + b_io[col + j];
            pk[j] = f2bf(siluf_(ln));
        }
        *reinterpret_cast<u16x4*>(h_pb + (long)row * 1024 + col) = *reinterpret_cast<u16x4*>(pk);
    }
}

// ---------------- host ----------------

extern "C" void kernel_launch(void* const* d_in, const int* in_sizes, int n_in,
                              void* d_out, int out_size, void* d_ws, size_t ws_size,
                              hipStream_t stream) {
    const float* embed      = (const float*)d_in[0];
    const float* action     = (const float*)d_in[1];
    const float* init_deter = (const float*)d_in[3];
    const float* init_stoch = (const float*)d_in[4];
    const float* noise_pr   = (const float*)d_in[5];
    const float* noise_po   = (const float*)d_in[6];
    const float* W_in       = (const float*)d_in[7];
    const float* g_in       = (const float*)d_in[8];
    const float* b_in       = (const float*)d_in[9];
    const float* W_gru      = (const float*)d_in[10];
    const float* g_gru      = (const float*)d_in[11];
    const float* b_gru      = (const float*)d_in[12];
    const float* W_io       = (const float*)d_in[13];
    const float* g_io       = (const float*)d_in[14];
    const float* b_io       = (const float*)d_in[15];
    const float* W_oo       = (const float*)d_in[16];
    const float* g_oo       = (const float*)d_in[17];
    const float* b_oo       = (const float*)d_in[18];
    const float* W_ims      = (const float*)d_in[19];
    const float* b_ims      = (const float*)d_in[20];
    const float* W_obs      = (const float*)d_in[21];
    const float* b_obs      = (const float*)d_in[22];
    float* out = (float*)d_out;

    char* ws = (char*)d_ws;
    size_t off = 0;
    auto alloc = [&](size_t bytes) {
        size_t r = off;
        off = (off + bytes + 255) & ~(size_t)255;
        return r;
    };
    unsigned short* pWgru  = (unsigned short*)(ws + alloc((size_t)5120 * 12288 * 2));
    unsigned short* pWin_s = (unsigned short*)(ws + alloc((size_t)1024 * 1024 * 2));
    unsigned short* pWin_a = (unsigned short*)(ws + alloc((size_t)128 * 1024 * 2));
    unsigned short* pWio   = (unsigned short*)(ws + alloc((size_t)4096 * 1024 * 2));
    unsigned short* pWood  = (unsigned short*)(ws + alloc((size_t)4096 * 1024 * 2));
    unsigned short* pWooe  = (unsigned short*)(ws + alloc((size_t)1536 * 1024 * 2));
    unsigned short* pWims  = (unsigned short*)(ws + alloc((size_t)1024 * 2048 * 2));
    unsigned short* pWobs  = (unsigned short*)(ws + alloc((size_t)1024 * 2048 * 2));
    unsigned short* act_bf = (unsigned short*)(ws + alloc((size_t)2048 * 128 * 2));
    unsigned short* emb_bf = (unsigned short*)(ws + alloc((size_t)2048 * 1536 * 2));
    float* A_pre  = (float*)(ws + alloc((size_t)2048 * 1024 * 4));
    float* E_pre  = (float*)(ws + alloc((size_t)2048 * 1024 * 4));
    float* x_raw  = (float*)(ws + alloc((size_t)32 * 1024 * 4));
    float* G_raw  = (float*)(ws + alloc((size_t)32 * GRUN * 4));
    float* hq_raw = (float*)(ws + alloc((size_t)32 * 1024 * 4));
    float* deterf = (float*)(ws + alloc((size_t)32 * DETER_ * 4));
    unsigned short* deterb     = (unsigned short*)(ws + alloc((size_t)32 * DETER_ * 2));
    unsigned short* deter_allb = (unsigned short*)(ws + alloc((size_t)2048 * DETER_ * 2));
    unsigned short* stochb = (unsigned short*)(ws + alloc((size_t)32 * 1024 * 2));
    float* hp_raw = (float*)(ws + alloc((size_t)2048 * 1024 * 4));
    unsigned short* h_pb = (unsigned short*)(ws + alloc((size_t)2048 * 1024 * 2));
    float* px  = (float*)(ws + alloc((size_t)32 * 32 * 2 * 4));
    float* pg  = (float*)(ws + alloc((size_t)384 * 32 * 2 * 4));
    float* ph  = (float*)(ws + alloc((size_t)32 * 32 * 2 * 4));
    float* pbh = (float*)(ws + alloc((size_t)32 * 2048 * 2 * 4));
    (void)ws_size; (void)out_size; (void)n_in; (void)in_sizes;

    auto packgrid = [](long K, long N) { return (unsigned)((K * N / 8 + 255) / 256); };

    // prep: pack weights
    k_pack<<<packgrid(5120, 12288), 256, 0, stream>>>(W_gru, pWgru, 5120, 12288);
    k_pack<<<packgrid(1024, 1024), 256, 0, stream>>>(W_in, pWin_s, 1024, 1024);
    k_pack<<<packgrid(128, 1024), 256, 0, stream>>>(W_in + (size_t)1024 * 1024, pWin_a, 128, 1024);
    k_pack<<<packgrid(4096, 1024), 256, 0, stream>>>(W_io, pWio, 4096, 1024);
    k_pack<<<packgrid(4096, 1024), 256, 0, stream>>>(W_oo, pWood, 4096, 1024);
    k_pack<<<packgrid(1536, 1024), 256, 0, stream>>>(W_oo + (size_t)4096 * 1024, pWooe, 1536, 1024);
    k_pack<<<packgrid(1024, 2048), 256, 0, stream>>>(W_ims, pWims, 1024, 2048);
    k_pack<<<packgrid(1024, 2048), 256, 0, stream>>>(W_obs, pWobs, 1024, 2048);
    // prep: conversions
    k_conv<<<(2048 * 128 / 4 + 255) / 256, 256, 0, stream>>>(action, act_bf, 2048L * 128);
    k_conv<<<(2048 * 1536 / 4 + 255) / 256, 256, 0, stream>>>(embed, emb_bf, 2048L * 1536);
    k_conv<<<(32 * 1024 / 4 + 255) / 256, 256, 0, stream>>>(init_stoch, stochb, 32L * 1024);
    k_conv<<<(32 * 4096 / 4 + 255) / 256, 256, 0, stream>>>(init_deter, deterb, 32L * 4096);
    k_copy<<<(32 * 4096 / 4 + 255) / 256, 256, 0, stream>>>(init_deter, deterf, 32L * 4096);
    // prep: time-invariant contributions  A_pre = act@Win_a ; E_pre = emb@Wooe
    k_gemm32<128, 1, 0><<<dim3(32, 64), 256, 0, stream>>>(
        pWin_a, 4, 0, act_bf, 128, nullptr, 0, nullptr, nullptr, nullptr, 0,
        nullptr, 0, A_pre, 1024, nullptr, 0);
    k_gemm32<512, 3, 0><<<dim3(32, 64), 256, 0, stream>>>(
        pWooe, 48, 0, emb_bf, 1536, nullptr, 0, nullptr, nullptr, nullptr, 0,
        nullptr, 0, E_pre, 1024, nullptr, 0);

    for (int t = 0; t < T_; ++t) {
        // x_raw = stoch@Win_s + A_pre[t]
        k_gemm32<512, 2, 0><<<dim3(32, 1), 256, 0, stream>>>(
            pWin_s, 32, 0, stochb, 1024, nullptr, 0, nullptr, nullptr, nullptr, 0,
            A_pre + (size_t)t * 1024, (long)T_ * 1024, x_raw, 1024, px, 32);
        // G_raw = [silu(LN(x)) | deter] @ Wgru
        k_gemm32<512, 8, 2><<<dim3(384, 1), 256, 0, stream>>>(
            pWgru, 160, 32, deterb, 4096, x_raw, 1024, g_in, b_in, px, 32,
            nullptr, 0, G_raw, GRUN, pg, 32);
        // gates -> deter
        k_deter<<<128, 256, 0, stream>>>(G_raw, pg, g_gru, b_gru, deterf, deterb,
                                         deter_allb, out, t);
        // hq_raw = deter@Wood + E_pre[t]
        k_gemm32<512, 8, 0><<<dim3(32, 1), 256, 0, stream>>>(
            pWood, 128, 0, deterb, 4096, nullptr, 0, nullptr, nullptr, nullptr, 0,
            E_pre + (size_t)t * 1024, (long)T_ * 1024, hq_raw, 1024, ph, 32);
        // posterior stats + sample
        k_statsq<<<32, 256, 0, stream>>>(pWobs, hq_raw, ph, g_oo, b_oo, b_obs,
                                         noise_po, out, stochb, t);
    }

    // batched prior chain (off critical path): hp_raw = deter_all@Wio
    k_gemm32<512, 8, 0><<<dim3(32, 64), 256, 0, stream>>>(
        pWio, 128, 0, deter_allb, 4096, nullptr, 0, nullptr, nullptr, nullptr, 0,
        nullptr, 0, hp_raw, 1024, pbh, 2048);
    k_bfin<<<256, 256, 0, stream>>>(hp_raw, pbh, g_io, b_io, h_pb);
    k_bstats<<<dim3(32, 64), 256, 0, stream>>>(pWims, h_pb, b_ims, noise_pr, out);
}